// Round 8
// baseline (291.039 us; speedup 1.0000x reference)
//
#include <hip/hip_runtime.h>
#include <hip/hip_bf16.h>
#include <cstdint>
#include <cstddef>

typedef __bf16 bf16_t;
typedef bf16_t bf16x8 __attribute__((ext_vector_type(8)));
typedef bf16_t bf16x4 __attribute__((ext_vector_type(4)));
typedef float f32x4 __attribute__((ext_vector_type(4)));

#define BN_EPS 1e-5f

// Async global->LDS, 16B per lane (wave-uniform LDS base; lane i -> base+i*16).
// NOTE (r7 lesson): per-lane global addresses must stay lane-order contiguous
// within 128B lines or request merging breaks and the staging path slows ~35%.
__device__ __forceinline__ void async_load16(const bf16_t* g, bf16_t* lds) {
  __builtin_amdgcn_global_load_lds(
      (__attribute__((address_space(1))) uint32_t*)(g),
      (__attribute__((address_space(3))) uint32_t*)(lds),
      16, 0, 0);
}

// ---- Merged prep ------------------------------------------------------------
// blocks 0..16383: x -> bf16 + conv feature + zero outacc (4 rows each)
// blocks 16384..16575: W1/W2 transpose+cast tiles
// blocks 16576..16579: BN fold, w1last, zero tile counters
__global__ void prep_kernel(const float* __restrict__ x, bf16_t* __restrict__ xb,
                            float* __restrict__ convf, float* __restrict__ outacc,
                            const float* __restrict__ W1, const float* __restrict__ W2,
                            const float* b1, const float* g1, const float* be1,
                            const float* m1, const float* v1,
                            const float* b2, const float* g2, const float* be2,
                            const float* m2, const float* v2,
                            bf16_t* __restrict__ W1T, bf16_t* __restrict__ W2T,
                            float* s1, float* t1, float* s2, float* t2,
                            float* w1last, unsigned int* cnt) {
  const int blk = blockIdx.x;
  if (blk < 16384) {
    int lane = threadIdx.x & 63;
    int w = threadIdx.x >> 6;
    int row = blk * 4 + w;
    const float4 v = *(const float4*)(x + (size_t)row * 256 + lane * 4);
    float s = v.x + v.y + v.z + v.w;
    bf16x4 o = {(bf16_t)v.x, (bf16_t)v.y, (bf16_t)v.z, (bf16_t)v.w};
    *(bf16x4*)(xb + (size_t)row * 256 + lane * 4) = o;
#pragma unroll
    for (int off = 32; off >= 1; off >>= 1) s += __shfl_down(s, off);
    if (lane == 0) convf[row] = (s > 0.0f) ? 1.0f : 0.0f;  // mean>0 <=> sum>0
    if (threadIdx.x < 4) outacc[blk * 4 + threadIdx.x] = 0.0f;
  } else if (blk < 16576) {
    const int b = blk - 16384;
    const float* src;
    bf16_t* dst;
    int R, C, bx, by;
    if (b < 64) { src = W1; dst = W1T; R = 256; C = 1024; bx = b & 15; by = b >> 4; }
    else        { src = W2; dst = W2T; R = 1024; C = 512; bx = (b - 64) & 7; by = (b - 64) >> 3; }
    __shared__ bf16_t tile[64][66];
    const int r0 = by * 64, c0 = bx * 64;
    const int tc = threadIdx.x & 63;
    const int tr4 = threadIdx.x >> 6;
#pragma unroll
    for (int i = 0; i < 16; ++i) {
      int r = i * 4 + tr4;
      tile[r][tc] = (bf16_t)src[(size_t)(r0 + r) * C + c0 + tc];  // coalesced read
    }
    __syncthreads();
#pragma unroll
    for (int i = 0; i < 16; ++i) {
      int rr = i * 4 + tr4;
      dst[(size_t)(c0 + rr) * R + r0 + tc] = tile[tc][rr];  // coalesced write
    }
  } else {
    int i = (blk - 16576) * 256 + threadIdx.x;
    if (i < 1024) {
      float s = g1[i] * rsqrtf(v1[i] + BN_EPS);
      s1[i] = s;
      t1[i] = be1[i] - m1[i] * s + b1[i] * s;  // bn(z+b1) = z*s + t
      w1last[i] = W1[256 * 1024 + i];          // conv-feature row (coalesced)
    }
    if (i < 512) {
      float s = g2[i] * rsqrtf(v2[i] + BN_EPS);
      s2[i] = s;
      t2[i] = be2[i] - m2[i] * s + b2[i] * s;
    }
    if (i < 256) cnt[i] = 0u;  // gemm2 per-M-tile completion counters
  }
}

// ---- Shared 256x128-tile GEMM core (r6-proven: BK=32, linear lanes) ---------
// A [M x K] bf16 K-contig, BT [N x K] bf16 K-contig. 4 waves; wave w computes
// rows [w*64, w*64+64) x all 128 cols. acc 4x8 f32x4.
template <int K>
__device__ __forceinline__ void gemm_core_256x128(
    const bf16_t* __restrict__ A, const bf16_t* __restrict__ BT,
    int mTile, int nTile, bf16_t* As, bf16_t* Bs,
    int w, int lane, f32x4 (&acc)[4][8]) {
  const int l15 = lane & 15;
  const int quad = lane >> 4;
  const int sRow = lane >> 2;
  const int sCol = (lane & 3) * 8;
  const bf16_t* gA = A + (size_t)(mTile + w * 64 + sRow) * K + sCol;
  const bf16_t* gB = BT + (size_t)(nTile + w * 32 + sRow) * K + sCol;
  bf16_t* lA = As + (w * 64) * 32;
  bf16_t* lB = Bs + (w * 32) * 32;

  for (int k0 = 0; k0 < K; k0 += 32) {
    async_load16(gA + k0, lA);
    async_load16(gA + (size_t)16 * K + k0, lA + 16 * 32);
    async_load16(gA + (size_t)32 * K + k0, lA + 32 * 32);
    async_load16(gA + (size_t)48 * K + k0, lA + 48 * 32);
    async_load16(gB + k0, lB);
    async_load16(gB + (size_t)16 * K + k0, lB + 16 * 32);
    __syncthreads();  // drains vmcnt before barrier

    bf16x8 af[4], bfr[8];
#pragma unroll
    for (int t = 0; t < 4; ++t)
      af[t] = *(const bf16x8*)(As + (w * 64 + t * 16 + l15) * 32 + quad * 8);
#pragma unroll
    for (int t = 0; t < 8; ++t)
      bfr[t] = *(const bf16x8*)(Bs + (t * 16 + l15) * 32 + quad * 8);
#pragma unroll
    for (int ti = 0; ti < 4; ++ti)
#pragma unroll
      for (int tj = 0; tj < 8; ++tj)
        acc[ti][tj] = __builtin_amdgcn_mfma_f32_16x16x32_bf16(af[ti], bfr[tj], acc[ti][tj], 0, 0, 0);
    __syncthreads();
  }
}

// ---- GEMM1: h1 = relu(bn1(xb @ W1T^T + conv rank-1)), bf16 out --------------
// Grid 2048, XCD-aware: same-XCD (b&7) blocks sweep the 8 N-tiles of one
// M-tile consecutively -> A-tile L2-resident per XCD.
__global__ __launch_bounds__(256, 2) void gemm1_kernel(
    const bf16_t* __restrict__ A, const bf16_t* __restrict__ BT,
    const float* __restrict__ sN, const float* __restrict__ tN,
    const float* __restrict__ convf, const float* __restrict__ w1last,
    bf16_t* __restrict__ out) {
  constexpr int K = 256, N = 1024;
  __shared__ __align__(16) bf16_t As[256 * 32];
  __shared__ __align__(16) bf16_t Bs[128 * 32];

  const int b = blockIdx.x;
  const int mTile = ((b >> 6) * 8 + (b & 7)) * 256;  // 256 M-tiles
  const int nTile = ((b >> 3) & 7) * 128;            // 8 N-tiles

  const int tid = threadIdx.x;
  const int lane = tid & 63;
  const int w = tid >> 6;
  const int l15 = lane & 15;
  const int quad = lane >> 4;

  f32x4 acc[4][8];
#pragma unroll
  for (int i = 0; i < 4; ++i)
#pragma unroll
    for (int j = 0; j < 8; ++j) {
      f32x4 z = {0.f, 0.f, 0.f, 0.f};
      acc[i][j] = z;
    }

  gemm_core_256x128<K>(A, BT, mTile, nTile, As, Bs, w, lane, acc);

  // Epilogue: conv rank-1 + BN1 + ReLU -> bf16. C/D: col=l15, row=quad*4+reg.
  float sc[8], tc[8], wl[8];
#pragma unroll
  for (int tj = 0; tj < 8; ++tj) {
    int c = nTile + tj * 16 + l15;
    sc[tj] = sN[c];
    tc[tj] = tN[c];
    wl[tj] = w1last[c];
  }
#pragma unroll
  for (int ti = 0; ti < 4; ++ti)
#pragma unroll
    for (int r = 0; r < 4; ++r) {
      int row = mTile + w * 64 + ti * 16 + quad * 4 + r;
      float cf = convf[row];
      size_t base = (size_t)row * N + nTile;
#pragma unroll
      for (int tj = 0; tj < 8; ++tj) {
        float z = acc[ti][tj][r] + cf * wl[tj];
        z = fmaxf(z * sc[tj] + tc[tj], 0.f);
        out[base + tj * 16 + l15] = (bf16_t)z;
      }
    }
}

// ---- GEMM2 + head + fused sigmoid -------------------------------------------
// Per-row partial logits via atomicAdd; the last of the 4 N-blocks of each
// M-tile (same XCD by swizzle) applies bias+sigmoid in-place.
__global__ __launch_bounds__(256, 2) void gemm2_head_kernel(
    const bf16_t* __restrict__ A, const bf16_t* __restrict__ BT,
    const float* __restrict__ sN, const float* __restrict__ tN,
    const float* __restrict__ W3, const float* __restrict__ b3,
    float* __restrict__ outacc, unsigned int* __restrict__ cnt) {
  constexpr int K = 1024;
  __shared__ __align__(16) bf16_t As[256 * 32];
  __shared__ __align__(16) bf16_t Bs[128 * 32];
  __shared__ int isLast;

  const int b = blockIdx.x;
  const int mt = (b >> 5) * 8 + (b & 7);             // M-tile index, XCD-grouped
  const int mTile = mt * 256;
  const int nTile = ((b >> 3) & 3) * 128;            // 4 N-tiles

  const int tid = threadIdx.x;
  const int lane = tid & 63;
  const int w = tid >> 6;
  const int l15 = lane & 15;
  const int quad = lane >> 4;

  f32x4 acc[4][8];
#pragma unroll
  for (int i = 0; i < 4; ++i)
#pragma unroll
    for (int j = 0; j < 8; ++j) {
      f32x4 z = {0.f, 0.f, 0.f, 0.f};
      acc[i][j] = z;
    }

  gemm_core_256x128<K>(A, BT, mTile, nTile, As, Bs, w, lane, acc);

  // Epilogue: per-row partial of relu(bn2)*W3 over this block's 128 cols.
  float sc[8], tc[8], w3c[8];
#pragma unroll
  for (int tj = 0; tj < 8; ++tj) {
    int c = nTile + tj * 16 + l15;
    sc[tj] = sN[c];
    tc[tj] = tN[c];
    w3c[tj] = W3[c];
  }
#pragma unroll
  for (int ti = 0; ti < 4; ++ti)
#pragma unroll
    for (int r = 0; r < 4; ++r) {
      float p = 0.f;
#pragma unroll
      for (int tj = 0; tj < 8; ++tj) {
        float z = fmaxf(acc[ti][tj][r] * sc[tj] + tc[tj], 0.f);
        p += z * w3c[tj];
      }
#pragma unroll
      for (int m = 1; m <= 8; m <<= 1) p += __shfl_xor(p, m);  // reduce 16 col-lanes
      if (l15 == 0)
        atomicAdd(outacc + mTile + w * 64 + ti * 16 + quad * 4 + r, p);
    }

  // Completion: counter handshake orders across the tile's 4 blocks
  // (device-scope atomics; same XCD by swizzle but fences are device-scope).
  __syncthreads();
  if (tid == 0) {
    __threadfence();
    unsigned int old = atomicAdd(&cnt[mt], 1u);
    isLast = (old == 3u) ? 1 : 0;
  }
  __syncthreads();
  if (isLast) {
    __threadfence();
    float z = __hip_atomic_load(&outacc[mTile + tid], __ATOMIC_RELAXED,
                                __HIP_MEMORY_SCOPE_AGENT) + b3[0];
    outacc[mTile + tid] = 1.0f / (1.0f + expf(-z));
  }
}

extern "C" void kernel_launch(void* const* d_in, const int* in_sizes, int n_in,
                              void* d_out, int out_size, void* d_ws, size_t ws_size,
                              hipStream_t stream) {
  const float* x = (const float*)d_in[0];
  const float* W1 = (const float*)d_in[1];
  const float* b1 = (const float*)d_in[2];
  const float* g1 = (const float*)d_in[3];
  const float* be1 = (const float*)d_in[4];
  const float* m1 = (const float*)d_in[5];
  const float* v1 = (const float*)d_in[6];
  const float* W2 = (const float*)d_in[7];
  const float* b2 = (const float*)d_in[8];
  const float* g2 = (const float*)d_in[9];
  const float* be2 = (const float*)d_in[10];
  const float* m2 = (const float*)d_in[11];
  const float* v2 = (const float*)d_in[12];
  const float* W3 = (const float*)d_in[13];
  const float* b3 = (const float*)d_in[14];
  float* out = (float*)d_out;  // doubles as the fp32 logit accumulator

  char* p = (char*)d_ws;
  bf16_t* h1 = (bf16_t*)p;    p += (size_t)65536 * 1024 * 2;  // 128 MB
  bf16_t* xb = (bf16_t*)p;    p += (size_t)65536 * 256 * 2;   // 32 MB
  bf16_t* W1T = (bf16_t*)p;   p += (size_t)1024 * 256 * 2;
  bf16_t* W2T = (bf16_t*)p;   p += (size_t)512 * 1024 * 2;
  float* convf = (float*)p;   p += (size_t)65536 * 4;
  float* w1last = (float*)p;  p += 1024 * 4;
  float* s1 = (float*)p;      p += 1024 * 4;
  float* t1 = (float*)p;      p += 1024 * 4;
  float* s2 = (float*)p;      p += 512 * 4;
  float* t2 = (float*)p;      p += 512 * 4;
  unsigned int* cnt = (unsigned int*)p;  p += 256 * 4;

  prep_kernel<<<16580, 256, 0, stream>>>(x, xb, convf, out,
                                         W1, W2, b1, g1, be1, m1, v1,
                                         b2, g2, be2, m2, v2,
                                         W1T, W2T, s1, t1, s2, t2, w1last, cnt);

  gemm1_kernel<<<2048, 256, 0, stream>>>(xb, W1T, s1, t1, convf, w1last, h1);
  gemm2_head_kernel<<<1024, 256, 0, stream>>>(h1, W2T, s2, t2, W3, b3, out, cnt);
}

// Round 9
// 259.129 us; speedup vs baseline: 1.1231x; 1.1231x over previous
//
#include <hip/hip_runtime.h>
#include <hip/hip_bf16.h>
#include <cstdint>
#include <cstddef>

typedef __bf16 bf16_t;
typedef bf16_t bf16x8 __attribute__((ext_vector_type(8)));
typedef bf16_t bf16x4 __attribute__((ext_vector_type(4)));
typedef float f32x4 __attribute__((ext_vector_type(4)));

#define BN_EPS 1e-5f

// Async global->LDS, 16B per lane (wave-uniform LDS base; lane i -> base+i*16).
// r7 lesson: the per-lane GLOBAL addresses must stay lane-order contiguous
// within 128B lines or request merging breaks (staging slowed ~35%). LDS-side
// swizzles are only legal on the explicit ds_write path.
// r8 lesson: __threadfence() on gfx950 is an L2-writeback-class op (XCD
// coherence) — never in a per-block epilogue.
__device__ __forceinline__ void async_load16(const bf16_t* g, bf16_t* lds) {
  __builtin_amdgcn_global_load_lds(
      (__attribute__((address_space(1))) uint32_t*)(g),
      (__attribute__((address_space(3))) uint32_t*)(lds),
      16, 0, 0);
}

// ---- Merged prep ------------------------------------------------------------
// blocks 0..16383: x -> bf16 + conv feature + zero outacc (4 rows each)
// blocks 16384..16575: W1/W2 transpose+cast tiles
// blocks 16576..16579: BN fold, w1last
__global__ void prep_kernel(const float* __restrict__ x, bf16_t* __restrict__ xb,
                            float* __restrict__ convf, float* __restrict__ outacc,
                            const float* __restrict__ W1, const float* __restrict__ W2,
                            const float* b1, const float* g1, const float* be1,
                            const float* m1, const float* v1,
                            const float* b2, const float* g2, const float* be2,
                            const float* m2, const float* v2,
                            bf16_t* __restrict__ W1T, bf16_t* __restrict__ W2T,
                            float* s1, float* t1, float* s2, float* t2,
                            float* w1last) {
  const int blk = blockIdx.x;
  if (blk < 16384) {
    int lane = threadIdx.x & 63;
    int w = threadIdx.x >> 6;
    int row = blk * 4 + w;
    const float4 v = *(const float4*)(x + (size_t)row * 256 + lane * 4);
    float s = v.x + v.y + v.z + v.w;
    bf16x4 o = {(bf16_t)v.x, (bf16_t)v.y, (bf16_t)v.z, (bf16_t)v.w};
    *(bf16x4*)(xb + (size_t)row * 256 + lane * 4) = o;
#pragma unroll
    for (int off = 32; off >= 1; off >>= 1) s += __shfl_down(s, off);
    if (lane == 0) convf[row] = (s > 0.0f) ? 1.0f : 0.0f;  // mean>0 <=> sum>0
    if (threadIdx.x < 4) outacc[blk * 4 + threadIdx.x] = 0.0f;
  } else if (blk < 16576) {
    const int b = blk - 16384;
    const float* src;
    bf16_t* dst;
    int R, C, bx, by;
    if (b < 64) { src = W1; dst = W1T; R = 256; C = 1024; bx = b & 15; by = b >> 4; }
    else        { src = W2; dst = W2T; R = 1024; C = 512; bx = (b - 64) & 7; by = (b - 64) >> 3; }
    __shared__ bf16_t tile[64][66];
    const int r0 = by * 64, c0 = bx * 64;
    const int tc = threadIdx.x & 63;
    const int tr4 = threadIdx.x >> 6;
#pragma unroll
    for (int i = 0; i < 16; ++i) {
      int r = i * 4 + tr4;
      tile[r][tc] = (bf16_t)src[(size_t)(r0 + r) * C + c0 + tc];  // coalesced read
    }
    __syncthreads();
#pragma unroll
    for (int i = 0; i < 16; ++i) {
      int rr = i * 4 + tr4;
      dst[(size_t)(c0 + rr) * R + r0 + tc] = tile[tc][rr];  // coalesced write
    }
  } else {
    int i = (blk - 16576) * 256 + threadIdx.x;
    if (i < 1024) {
      float s = g1[i] * rsqrtf(v1[i] + BN_EPS);
      s1[i] = s;
      t1[i] = be1[i] - m1[i] * s + b1[i] * s;  // bn(z+b1) = z*s + t
      w1last[i] = W1[256 * 1024 + i];          // conv-feature row (coalesced)
    }
    if (i < 512) {
      float s = g2[i] * rsqrtf(v2[i] + BN_EPS);
      s2[i] = s;
      t2[i] = be2[i] - m2[i] * s + b2[i] * s;
    }
  }
}

// ---- GEMM1, A-resident: h1 = relu(bn1(xb @ W1T^T + conv rank-1)) ------------
// 512 blocks x 128 rows. The full A-stripe (128x256 bf16 = 64 KB) is staged
// ONCE into LDS (XOR-chunk swizzle for bank spread; global side linear).
// Wave pair p = {w0,w1} sweeps N-chunks p*4..p*4+3 (128 cols each); only B
// (L2-hot W1T) is staged inside the K-loop. Per iter/wave: 32 MFMA, 12
// ds_read_b128, 4 async B loads. LDS = 64 + 16 KB = 80 KB -> 2 blocks/CU.
__global__ __launch_bounds__(256, 2) void gemm1_kernel(
    const bf16_t* __restrict__ xb, const bf16_t* __restrict__ W1T,
    const float* __restrict__ s1, const float* __restrict__ t1,
    const float* __restrict__ convf, const float* __restrict__ w1last,
    bf16_t* __restrict__ h1) {
  __shared__ __align__(16) bf16_t As[128 * 256];   // 64 KB, chunk-swizzled
  __shared__ __align__(16) bf16_t Bs[2][128 * 32]; // 16 KB

  const int tid = threadIdx.x;
  const int lane = tid & 63;
  const int w = tid >> 6;        // wave 0..3
  const int p = w >> 1;          // pair 0..1
  const int h = w & 1;           // row-half within pair
  const int l15 = lane & 15;
  const int quad = lane >> 4;
  const int mTile = blockIdx.x * 128;

  // ---- Prologue: stage A-stripe once (regular loads + swizzled ds_write) ----
  // Per inst: 2 rows x 32 chunks of 8 elems. chunk' = chunk ^ (row&7).
  {
    const int rsub = lane >> 5;         // 0..1
    const int c = lane & 31;            // chunk within row
#pragma unroll
    for (int i = 0; i < 16; ++i) {
      int row = w * 32 + i * 2 + rsub;
      bf16x8 v = *(const bf16x8*)(xb + (size_t)(mTile + row) * 256 + c * 8);
      *(bf16x8*)&As[row * 256 + (c ^ (row & 7)) * 8] = v;
    }
  }

  const float b3dummy = 0.f; (void)b3dummy;

  for (int j = 0; j < 4; ++j) {
    const int colbase = (p * 4 + j) * 128;
    f32x4 acc[4][8];
#pragma unroll
    for (int i = 0; i < 4; ++i)
#pragma unroll
      for (int t = 0; t < 8; ++t) {
        f32x4 z = {0.f, 0.f, 0.f, 0.f};
        acc[i][t] = z;
      }

    const bf16_t* gB = W1T + (size_t)(colbase + h * 64 + (lane >> 2)) * 256 + (lane & 3) * 8;
    bf16_t* lB = Bs[p] + (h * 64) * 32;

    for (int ks = 0; ks < 8; ++ks) {
      __syncthreads();  // previous iter's Bs readers done (also covers prologue)
#pragma unroll
      for (int i = 0; i < 4; ++i)   // 64 rows x 32 k per wave
        async_load16(gB + (size_t)(i * 16) * 256 + ks * 32, lB + (i * 16) * 32);
      __syncthreads();  // drain

      bf16x8 af[4], bfr[8];
#pragma unroll
      for (int ti = 0; ti < 4; ++ti) {
        int row = h * 64 + ti * 16 + l15;
        af[ti] = *(const bf16x8*)&As[row * 256 + ((ks * 4 + quad) ^ (l15 & 7)) * 8];
      }
#pragma unroll
      for (int tj = 0; tj < 8; ++tj)
        bfr[tj] = *(const bf16x8*)(Bs[p] + (tj * 16 + l15) * 32 + quad * 8);
#pragma unroll
      for (int ti = 0; ti < 4; ++ti)
#pragma unroll
        for (int tj = 0; tj < 8; ++tj)
          acc[ti][tj] = __builtin_amdgcn_mfma_f32_16x16x32_bf16(af[ti], bfr[tj], acc[ti][tj], 0, 0, 0);
    }

    // Per-chunk epilogue: conv rank-1 + BN1 + ReLU -> h1 (bf16)
    float sc[8], tc[8], wl[8];
#pragma unroll
    for (int tj = 0; tj < 8; ++tj) {
      int c = colbase + tj * 16 + l15;
      sc[tj] = s1[c];
      tc[tj] = t1[c];
      wl[tj] = w1last[c];
    }
#pragma unroll
    for (int ti = 0; ti < 4; ++ti)
#pragma unroll
      for (int r = 0; r < 4; ++r) {
        int row = mTile + h * 64 + ti * 16 + quad * 4 + r;
        float cf = convf[row];
        size_t base = (size_t)row * 1024 + colbase;
#pragma unroll
        for (int tj = 0; tj < 8; ++tj) {
          float z = acc[ti][tj][r] + cf * wl[tj];
          z = fmaxf(z * sc[tj] + tc[tj], 0.f);
          h1[base + tj * 16 + l15] = (bf16_t)z;
        }
      }
  }
}

// ---- GEMM2 + head (r6-proven, 82.7 us): 256x128 tile, atomicAdd logits -----
__global__ __launch_bounds__(256, 2) void gemm2_head_kernel(
    const bf16_t* __restrict__ A, const bf16_t* __restrict__ BT,
    const float* __restrict__ sN, const float* __restrict__ tN,
    const float* __restrict__ W3, float* __restrict__ outacc) {
  constexpr int K = 1024;
  __shared__ __align__(16) bf16_t As[256 * 32];
  __shared__ __align__(16) bf16_t Bs[128 * 32];

  const int b = blockIdx.x;
  const int mTile = ((b >> 5) * 8 + (b & 7)) * 256;  // 256 M-tiles, XCD-grouped
  const int nTile = ((b >> 3) & 3) * 128;            // 4 N-tiles

  const int tid = threadIdx.x;
  const int lane = tid & 63;
  const int w = tid >> 6;
  const int l15 = lane & 15;
  const int quad = lane >> 4;
  const int sRow = lane >> 2;
  const int sCol = (lane & 3) * 8;

  const bf16_t* gA = A + (size_t)(mTile + w * 64 + sRow) * K + sCol;
  const bf16_t* gB = BT + (size_t)(nTile + w * 32 + sRow) * K + sCol;
  bf16_t* lA = As + (w * 64) * 32;
  bf16_t* lB = Bs + (w * 32) * 32;

  f32x4 acc[4][8];
#pragma unroll
  for (int i = 0; i < 4; ++i)
#pragma unroll
    for (int j = 0; j < 8; ++j) {
      f32x4 z = {0.f, 0.f, 0.f, 0.f};
      acc[i][j] = z;
    }

  for (int k0 = 0; k0 < K; k0 += 32) {
    async_load16(gA + k0, lA);
    async_load16(gA + (size_t)16 * K + k0, lA + 16 * 32);
    async_load16(gA + (size_t)32 * K + k0, lA + 32 * 32);
    async_load16(gA + (size_t)48 * K + k0, lA + 48 * 32);
    async_load16(gB + k0, lB);
    async_load16(gB + (size_t)16 * K + k0, lB + 16 * 32);
    __syncthreads();

    bf16x8 af[4], bfr[8];
#pragma unroll
    for (int t = 0; t < 4; ++t)
      af[t] = *(const bf16x8*)(As + (w * 64 + t * 16 + l15) * 32 + quad * 8);
#pragma unroll
    for (int t = 0; t < 8; ++t)
      bfr[t] = *(const bf16x8*)(Bs + (t * 16 + l15) * 32 + quad * 8);
#pragma unroll
    for (int ti = 0; ti < 4; ++ti)
#pragma unroll
      for (int tj = 0; tj < 8; ++tj)
        acc[ti][tj] = __builtin_amdgcn_mfma_f32_16x16x32_bf16(af[ti], bfr[tj], acc[ti][tj], 0, 0, 0);
    __syncthreads();
  }

  float sc[8], tc[8], w3c[8];
#pragma unroll
  for (int tj = 0; tj < 8; ++tj) {
    int c = nTile + tj * 16 + l15;
    sc[tj] = sN[c];
    tc[tj] = tN[c];
    w3c[tj] = W3[c];
  }
#pragma unroll
  for (int ti = 0; ti < 4; ++ti)
#pragma unroll
    for (int r = 0; r < 4; ++r) {
      float p = 0.f;
#pragma unroll
      for (int tj = 0; tj < 8; ++tj) {
        float z = fmaxf(acc[ti][tj][r] * sc[tj] + tc[tj], 0.f);
        p += z * w3c[tj];
      }
#pragma unroll
      for (int m = 1; m <= 8; m <<= 1) p += __shfl_xor(p, m);
      if (l15 == 0)
        atomicAdd(outacc + mTile + w * 64 + ti * 16 + quad * 4 + r, p);
    }
}

// ---- Final sigmoid over accumulated logits ----------------------------------
__global__ void sigmoid_kernel(float* __restrict__ out, const float* __restrict__ b3) {
  int i = blockIdx.x * 256 + threadIdx.x;
  float z = out[i] + b3[0];
  out[i] = 1.0f / (1.0f + expf(-z));
}

extern "C" void kernel_launch(void* const* d_in, const int* in_sizes, int n_in,
                              void* d_out, int out_size, void* d_ws, size_t ws_size,
                              hipStream_t stream) {
  const float* x = (const float*)d_in[0];
  const float* W1 = (const float*)d_in[1];
  const float* b1 = (const float*)d_in[2];
  const float* g1 = (const float*)d_in[3];
  const float* be1 = (const float*)d_in[4];
  const float* m1 = (const float*)d_in[5];
  const float* v1 = (const float*)d_in[6];
  const float* W2 = (const float*)d_in[7];
  const float* b2 = (const float*)d_in[8];
  const float* g2 = (const float*)d_in[9];
  const float* be2 = (const float*)d_in[10];
  const float* m2 = (const float*)d_in[11];
  const float* v2 = (const float*)d_in[12];
  const float* W3 = (const float*)d_in[13];
  const float* b3 = (const float*)d_in[14];
  float* out = (float*)d_out;  // doubles as the fp32 logit accumulator

  char* p = (char*)d_ws;
  bf16_t* h1 = (bf16_t*)p;    p += (size_t)65536 * 1024 * 2;  // 128 MB
  bf16_t* xb = (bf16_t*)p;    p += (size_t)65536 * 256 * 2;   // 32 MB
  bf16_t* W1T = (bf16_t*)p;   p += (size_t)1024 * 256 * 2;
  bf16_t* W2T = (bf16_t*)p;   p += (size_t)512 * 1024 * 2;
  float* convf = (float*)p;   p += (size_t)65536 * 4;
  float* w1last = (float*)p;  p += 1024 * 4;
  float* s1 = (float*)p;      p += 1024 * 4;
  float* t1 = (float*)p;      p += 1024 * 4;
  float* s2 = (float*)p;      p += 512 * 4;
  float* t2 = (float*)p;      p += 512 * 4;

  prep_kernel<<<16580, 256, 0, stream>>>(x, xb, convf, out,
                                         W1, W2, b1, g1, be1, m1, v1,
                                         b2, g2, be2, m2, v2,
                                         W1T, W2T, s1, t1, s2, t2, w1last);

  gemm1_kernel<<<512, 256, 0, stream>>>(xb, W1T, s1, t1, convf, w1last, h1);
  gemm2_head_kernel<<<1024, 256, 0, stream>>>(h1, W2T, s2, t2, W3, out);

  sigmoid_kernel<<<256, 256, 0, stream>>>(out, b3);
}

// Round 11
// 247.945 us; speedup vs baseline: 1.1738x; 1.0451x over previous
//
#include <hip/hip_runtime.h>
#include <hip/hip_bf16.h>
#include <hip/hip_cooperative_groups.h>
#include <cstdint>
#include <cstddef>

namespace cg = cooperative_groups;

typedef __bf16 bf16_t;
typedef bf16_t bf16x8 __attribute__((ext_vector_type(8)));
typedef float f32x4 __attribute__((ext_vector_type(4)));

#define BN_EPS 1e-5f

// r7 lesson: per-lane GLOBAL addresses for global_load_lds must stay
// lane-order contiguous within 128B lines (request merging); LDS swizzles only
// on explicit ds_write paths.
// r8 lesson: __threadfence() is an L2-writeback-class op on gfx950 — never in
// a per-block epilogue. Cross-block handoff: dispatch boundary or grid.sync().
// r10 lesson: hipLaunchCooperativeKernel can reject the launch silently at
// exactly-full LDS occupancy — validate with host-side occupancy query and
// keep a fallback path.
__device__ __forceinline__ void async_load16(const bf16_t* g, bf16_t* lds) {
  __builtin_amdgcn_global_load_lds(
      (__attribute__((address_space(1))) uint32_t*)(g),
      (__attribute__((address_space(3))) uint32_t*)(lds),
      16, 0, 0);
}

// ---- Weight prep (transposes + BN folds), tiny ------------------------------
__global__ void prep_weights_kernel(const float* __restrict__ W1, const float* __restrict__ W2,
                                    const float* b1, const float* g1, const float* be1,
                                    const float* m1, const float* v1,
                                    const float* b2, const float* g2, const float* be2,
                                    const float* m2, const float* v2,
                                    bf16_t* __restrict__ W1T, bf16_t* __restrict__ W2T,
                                    float* s1, float* t1, float* s2, float* t2,
                                    float* w1last) {
  const int b = blockIdx.x;
  if (b < 192) {
    const float* src;
    bf16_t* dst;
    int R, C, bx, by;
    if (b < 64) { src = W1; dst = W1T; R = 256; C = 1024; bx = b & 15; by = b >> 4; }
    else        { src = W2; dst = W2T; R = 1024; C = 512; bx = (b - 64) & 7; by = (b - 64) >> 3; }
    __shared__ bf16_t tile[64][66];
    const int r0 = by * 64, c0 = bx * 64;
    const int tc = threadIdx.x & 63;
    const int tr4 = threadIdx.x >> 6;
#pragma unroll
    for (int i = 0; i < 16; ++i) {
      int r = i * 4 + tr4;
      tile[r][tc] = (bf16_t)src[(size_t)(r0 + r) * C + c0 + tc];  // coalesced read
    }
    __syncthreads();
#pragma unroll
    for (int i = 0; i < 16; ++i) {
      int rr = i * 4 + tr4;
      dst[(size_t)(c0 + rr) * R + r0 + tc] = tile[tc][rr];  // coalesced write
    }
  } else {
    for (int i = threadIdx.x; i < 1024; i += 256) {
      float s = g1[i] * rsqrtf(v1[i] + BN_EPS);
      s1[i] = s;
      t1[i] = be1[i] - m1[i] * s + b1[i] * s;  // bn(z+b1) = z*s + t
      w1last[i] = W1[256 * 1024 + i];          // conv-feature row (coalesced)
      if (i < 512) {
        float s2v = g2[i] * rsqrtf(v2[i] + BN_EPS);
        s2[i] = s2v;
        t2[i] = be2[i] - m2[i] * s2v + b2[i] * s2v;
      }
    }
  }
}

// ---- gemm1 body: A-resident, x cast+conv fused into prologue ----------------
// 128 rows/tile. As = 64 KB (chunk-swizzled), Bs = 2x8 KB. smem >= 80 KB.
__device__ __forceinline__ void gemm1_body(
    const float* __restrict__ x, const bf16_t* __restrict__ W1T,
    const float* __restrict__ s1, const float* __restrict__ t1,
    const float* __restrict__ w1last, bf16_t* __restrict__ h1,
    unsigned char* smem, int mTile, int lane, int w) {
  bf16_t* As = (bf16_t*)smem;                 // [128][256], chunk-swizzled
  bf16_t* BsBase = (bf16_t*)(smem + 65536);   // Bs[2][128*32]
  float* convs = (float*)(smem + 65536);      // transient, pre-staging
  const int l15 = lane & 15;
  const int quad = lane >> 4;
  const int p = w >> 1;        // wave pair 0..1
  const int h = w & 1;         // row-half within pair

  // Prologue: read x fp32, cast->bf16 into As (swizzled), per-row conv.
  {
    const int rsub = lane >> 5;     // 0..1
    const int c = lane & 31;        // 8-elem chunk within row
#pragma unroll
    for (int i = 0; i < 16; ++i) {
      int row = w * 32 + i * 2 + rsub;
      const float* gx = x + (size_t)(mTile + row) * 256 + c * 8;
      const float4 a = *(const float4*)gx;
      const float4 bq = *(const float4*)(gx + 4);
      float s = a.x + a.y + a.z + a.w + bq.x + bq.y + bq.z + bq.w;
      bf16x8 v = {(bf16_t)a.x, (bf16_t)a.y, (bf16_t)a.z, (bf16_t)a.w,
                  (bf16_t)bq.x, (bf16_t)bq.y, (bf16_t)bq.z, (bf16_t)bq.w};
      *(bf16x8*)(As + row * 256 + (c ^ (row & 7)) * 8) = v;
#pragma unroll
      for (int m = 1; m <= 16; m <<= 1) s += __shfl_xor(s, m);  // 32-lane groups
      if (c == 0) convs[row] = (s > 0.0f) ? 1.0f : 0.0f;  // mean>0 <=> sum>0
    }
  }
  __syncthreads();
  float cf[4][4];
#pragma unroll
  for (int ti = 0; ti < 4; ++ti)
#pragma unroll
    for (int r = 0; r < 4; ++r)
      cf[ti][r] = convs[h * 64 + ti * 16 + quad * 4 + r];

  for (int j = 0; j < 4; ++j) {
    const int colbase = (p * 4 + j) * 128;
    f32x4 acc[4][8];
#pragma unroll
    for (int i = 0; i < 4; ++i)
#pragma unroll
      for (int t = 0; t < 8; ++t) {
        f32x4 z = {0.f, 0.f, 0.f, 0.f};
        acc[i][t] = z;
      }

    const bf16_t* gB = W1T + (size_t)(colbase + h * 64 + (lane >> 2)) * 256 + (lane & 3) * 8;
    bf16_t* lB = BsBase + p * (128 * 32) + (h * 64) * 32;

    for (int ks = 0; ks < 8; ++ks) {
      __syncthreads();  // prior readers of Bs (or convs/cf) done
#pragma unroll
      for (int i = 0; i < 4; ++i)
        async_load16(gB + (size_t)(i * 16) * 256 + ks * 32, lB + (i * 16) * 32);
      __syncthreads();  // drain

      bf16x8 af[4], bfr[8];
#pragma unroll
      for (int ti = 0; ti < 4; ++ti) {
        int row = h * 64 + ti * 16 + l15;
        af[ti] = *(const bf16x8*)(As + row * 256 + ((ks * 4 + quad) ^ (l15 & 7)) * 8);
      }
#pragma unroll
      for (int tj = 0; tj < 8; ++tj)
        bfr[tj] = *(const bf16x8*)(BsBase + p * (128 * 32) + (tj * 16 + l15) * 32 + quad * 8);
#pragma unroll
      for (int ti = 0; ti < 4; ++ti)
#pragma unroll
        for (int tj = 0; tj < 8; ++tj)
          acc[ti][tj] = __builtin_amdgcn_mfma_f32_16x16x32_bf16(af[ti], bfr[tj], acc[ti][tj], 0, 0, 0);
    }

    // Per-chunk epilogue: conv rank-1 + BN1 + ReLU -> h1 (bf16)
    float sc[8], tc[8], wl[8];
#pragma unroll
    for (int tj = 0; tj < 8; ++tj) {
      int c = colbase + tj * 16 + l15;
      sc[tj] = s1[c];
      tc[tj] = t1[c];
      wl[tj] = w1last[c];
    }
#pragma unroll
    for (int ti = 0; ti < 4; ++ti)
#pragma unroll
      for (int r = 0; r < 4; ++r) {
        int row = mTile + h * 64 + ti * 16 + quad * 4 + r;
        size_t base = (size_t)row * 1024 + colbase;
#pragma unroll
        for (int tj = 0; tj < 8; ++tj) {
          float z = acc[ti][tj][r] + cf[ti][r] * wl[tj];
          z = fmaxf(z * sc[tj] + tc[tj], 0.f);
          h1[base + tj * 16 + l15] = (bf16_t)z;
        }
      }
  }
}

// ---- gemm2 task body (r6 core): one 256x128 tile -> per-N partials ----------
// smem >= 24 KB (As2 16 KB + Bs2 8 KB). Plain stores, no atomics/fences.
__device__ __forceinline__ void gemm2_task_body(
    const bf16_t* __restrict__ h1, const bf16_t* __restrict__ W2T,
    const float* __restrict__ s2, const float* __restrict__ t2,
    const float* __restrict__ W3, float* __restrict__ partials,
    unsigned char* smem, int task, int lane, int w) {
  bf16_t* As2 = (bf16_t*)smem;            // [256][32]
  bf16_t* Bs2 = (bf16_t*)(smem + 16384);  // [128][32]
  const int l15 = lane & 15;
  const int quad = lane >> 4;
  const int sRow = lane >> 2;
  const int sCol = (lane & 3) * 8;

  const int mt = (task >> 5) * 8 + (task & 7);   // XCD-grouped M-tile
  const int mTile2 = mt * 256;
  const int nt = (task >> 3) & 3;
  const int nTile = nt * 128;

  const bf16_t* gA = h1 + (size_t)(mTile2 + w * 64 + sRow) * 1024 + sCol;
  const bf16_t* gB = W2T + (size_t)(nTile + w * 32 + sRow) * 1024 + sCol;
  bf16_t* lA = As2 + (w * 64) * 32;
  bf16_t* lB = Bs2 + (w * 32) * 32;

  f32x4 acc[4][8];
#pragma unroll
  for (int i = 0; i < 4; ++i)
#pragma unroll
    for (int j = 0; j < 8; ++j) {
      f32x4 z = {0.f, 0.f, 0.f, 0.f};
      acc[i][j] = z;
    }

  for (int k0 = 0; k0 < 1024; k0 += 32) {
    async_load16(gA + k0, lA);
    async_load16(gA + (size_t)16 * 1024 + k0, lA + 16 * 32);
    async_load16(gA + (size_t)32 * 1024 + k0, lA + 32 * 32);
    async_load16(gA + (size_t)48 * 1024 + k0, lA + 48 * 32);
    async_load16(gB + k0, lB);
    async_load16(gB + (size_t)16 * 1024 + k0, lB + 16 * 32);
    __syncthreads();

    bf16x8 af[4], bfr[8];
#pragma unroll
    for (int t = 0; t < 4; ++t)
      af[t] = *(const bf16x8*)(As2 + (w * 64 + t * 16 + l15) * 32 + quad * 8);
#pragma unroll
    for (int t = 0; t < 8; ++t)
      bfr[t] = *(const bf16x8*)(Bs2 + (t * 16 + l15) * 32 + quad * 8);
#pragma unroll
    for (int ti = 0; ti < 4; ++ti)
#pragma unroll
      for (int tj = 0; tj < 8; ++tj)
        acc[ti][tj] = __builtin_amdgcn_mfma_f32_16x16x32_bf16(af[ti], bfr[tj], acc[ti][tj], 0, 0, 0);
    __syncthreads();
  }

  float sc[8], tc[8], w3c[8];
#pragma unroll
  for (int tj = 0; tj < 8; ++tj) {
    int c = nTile + tj * 16 + l15;
    sc[tj] = s2[c];
    tc[tj] = t2[c];
    w3c[tj] = W3[c];
  }
#pragma unroll
  for (int ti = 0; ti < 4; ++ti)
#pragma unroll
    for (int r = 0; r < 4; ++r) {
      float pv = 0.f;
#pragma unroll
      for (int tj = 0; tj < 8; ++tj) {
        float z = fmaxf(acc[ti][tj][r] * sc[tj] + tc[tj], 0.f);
        pv += z * w3c[tj];
      }
#pragma unroll
      for (int m = 1; m <= 8; m <<= 1) pv += __shfl_xor(pv, m);
      if (l15 == 0)
        partials[(size_t)nt * 65536 + mTile2 + w * 64 + ti * 16 + quad * 4 + r] = pv;
    }
}

// ---- Standalone wrappers (fallback path) ------------------------------------
__global__ __launch_bounds__(256, 2) void gemm1_kernel(
    const float* __restrict__ x, const bf16_t* __restrict__ W1T,
    const float* __restrict__ s1, const float* __restrict__ t1,
    const float* __restrict__ w1last, bf16_t* __restrict__ h1) {
  __shared__ __align__(16) unsigned char smem[81920];
  gemm1_body(x, W1T, s1, t1, w1last, h1, smem, blockIdx.x * 128,
             threadIdx.x & 63, threadIdx.x >> 6);
}

__global__ __launch_bounds__(256, 2) void gemm2_kernel(
    const bf16_t* __restrict__ h1, const bf16_t* __restrict__ W2T,
    const float* __restrict__ s2, const float* __restrict__ t2,
    const float* __restrict__ W3, float* __restrict__ partials) {
  __shared__ __align__(16) unsigned char smem[24576];
  gemm2_task_body(h1, W2T, s2, t2, W3, partials, smem, blockIdx.x,
                  threadIdx.x & 63, threadIdx.x >> 6);
}

__global__ void sigmoid_partials_kernel(const float* __restrict__ partials,
                                        const float* __restrict__ b3,
                                        float* __restrict__ out) {
  int i = blockIdx.x * 256 + threadIdx.x;
  float z = partials[i] + partials[65536 + i] + partials[2 * 65536 + i] +
            partials[3 * 65536 + i] + b3[0];
  out[i] = 1.0f / (1.0f + expf(-z));
}

// ---- Cooperative fused path -------------------------------------------------
__global__ __launch_bounds__(256, 2) void fused_mlp_coop(
    const float* __restrict__ x,
    const bf16_t* __restrict__ W1T, const bf16_t* __restrict__ W2T,
    const float* __restrict__ s1, const float* __restrict__ t1,
    const float* __restrict__ w1last,
    const float* __restrict__ s2, const float* __restrict__ t2,
    const float* __restrict__ W3, const float* __restrict__ b3,
    bf16_t* __restrict__ h1, float* __restrict__ partials,
    float* __restrict__ out) {
  __shared__ __align__(16) unsigned char smem[81920];
  cg::grid_group grid = cg::this_grid();
  const int tid = threadIdx.x;
  const int lane = tid & 63;
  const int w = tid >> 6;

  gemm1_body(x, W1T, s1, t1, w1last, h1, smem, blockIdx.x * 128, lane, w);

  grid.sync();  // h1 visible grid-wide

  gemm2_task_body(h1, W2T, s2, t2, W3, partials, smem, blockIdx.x, lane, w);
  gemm2_task_body(h1, W2T, s2, t2, W3, partials, smem, blockIdx.x + 512, lane, w);

  grid.sync();  // partials visible

  if (tid < 128) {
    int r = blockIdx.x * 128 + tid;
    float z = partials[r] + partials[65536 + r] + partials[2 * 65536 + r] +
              partials[3 * 65536 + r] + b3[0];
    out[r] = 1.0f / (1.0f + expf(-z));
  }
}

extern "C" void kernel_launch(void* const* d_in, const int* in_sizes, int n_in,
                              void* d_out, int out_size, void* d_ws, size_t ws_size,
                              hipStream_t stream) {
  const float* x = (const float*)d_in[0];
  const float* W1 = (const float*)d_in[1];
  const float* b1 = (const float*)d_in[2];
  const float* g1 = (const float*)d_in[3];
  const float* be1 = (const float*)d_in[4];
  const float* m1 = (const float*)d_in[5];
  const float* v1 = (const float*)d_in[6];
  const float* W2 = (const float*)d_in[7];
  const float* b2 = (const float*)d_in[8];
  const float* g2 = (const float*)d_in[9];
  const float* be2 = (const float*)d_in[10];
  const float* m2 = (const float*)d_in[11];
  const float* v2 = (const float*)d_in[12];
  const float* W3 = (const float*)d_in[13];
  const float* b3 = (const float*)d_in[14];
  float* out = (float*)d_out;

  char* p = (char*)d_ws;
  bf16_t* h1 = (bf16_t*)p;       p += (size_t)65536 * 1024 * 2;  // 128 MB
  float* partials = (float*)p;   p += (size_t)4 * 65536 * 4;     // 1 MB
  bf16_t* W1T = (bf16_t*)p;      p += (size_t)1024 * 256 * 2;
  bf16_t* W2T = (bf16_t*)p;      p += (size_t)512 * 1024 * 2;
  float* w1last = (float*)p;     p += 1024 * 4;
  float* s1 = (float*)p;         p += 1024 * 4;
  float* t1 = (float*)p;         p += 1024 * 4;
  float* s2 = (float*)p;         p += 512 * 4;
  float* t2 = (float*)p;         p += 512 * 4;

  prep_weights_kernel<<<193, 256, 0, stream>>>(W1, W2, b1, g1, be1, m1, v1,
                                               b2, g2, be2, m2, v2,
                                               W1T, W2T, s1, t1, s2, t2, w1last);

  // Host-side (capture-safe) validation of the cooperative path.
  int dev = 0;
  (void)hipGetDevice(&dev);
  int coopOk = 0;
  (void)hipDeviceGetAttribute(&coopOk, hipDeviceAttributeCooperativeLaunch, dev);
  int numCU = 0;
  (void)hipDeviceGetAttribute(&numCU, hipDeviceAttributeMultiprocessorCount, dev);
  int maxBlk = 0;
  (void)hipOccupancyMaxActiveBlocksPerMultiprocessor(&maxBlk, fused_mlp_coop, 256, 0);

  bool useCoop = (coopOk != 0) && ((long)maxBlk * (long)numCU >= 512L);
  if (useCoop) {
    void* args[] = {(void*)&x, (void*)&W1T, (void*)&W2T, (void*)&s1, (void*)&t1,
                    (void*)&w1last, (void*)&s2, (void*)&t2, (void*)&W3, (void*)&b3,
                    (void*)&h1, (void*)&partials, (void*)&out};
    hipError_t e = hipLaunchCooperativeKernel((const void*)fused_mlp_coop,
                                              dim3(512), dim3(256), args, 0, stream);
    if (e != hipSuccess) useCoop = false;
  }
  if (!useCoop) {
    gemm1_kernel<<<512, 256, 0, stream>>>(x, W1T, s1, t1, w1last, h1);
    gemm2_kernel<<<1024, 256, 0, stream>>>(h1, W2T, s2, t2, W3, partials);
    sigmoid_partials_kernel<<<256, 256, 0, stream>>>(partials, b3, out);
  }
}